// Round 4
// baseline (450.200 us; speedup 1.0000x reference)
//
#include <hip/hip_runtime.h>

typedef unsigned short u16;
using s8v = __attribute__((ext_vector_type(8))) short;   // 8 x bf16 (4 VGPRs)
using f4v = __attribute__((ext_vector_type(4))) float;   // MFMA accumulator

constexpr int kN = 32, kC = 256, kT = 256, kV = 25, kCI = 128;
constexpr int kTV = kT * kV;        // 6400
constexpr int kSAMP = kN * kT * kV; // 204800
constexpr int SYY_B = 256;          // 32 n * 8 chunks, 800 k each (1 block/CU)

__device__ __forceinline__ float bf2f(u16 v) {
  return __uint_as_float(((unsigned)v) << 16);
}
__device__ __forceinline__ u16 f2bf(float f) {
  unsigned u = __float_as_uint(f);
  return (u16)((u + 0x7FFFu + ((u >> 16) & 1u)) >> 16);
}

// ---------- 1) prep: x -> x_fl (c-frag-linear bf16) + xmean over V ----------
// block = (n, cg): 8 channels c = cg*8..+7, all 6400 cols, in 4 chunks of 1600.
__global__ __launch_bounds__(256) void k_prep(const float* __restrict__ x, u16* __restrict__ x_fl,
                                              float* __restrict__ xm) {
  __shared__ float sm[8][1600];
  const int n = blockIdx.x >> 5, cg = blockIdx.x & 31;
  const int tid = threadIdx.x;
  u16* xfn = x_fl + (size_t)n * (kC / 8) * kTV * 8;
  for (int chunk = 0; chunk < 4; ++chunk) {
    const int col0 = chunk * 1600;
    for (int e = tid; e < 3200; e += 256) {
      int r = e / 400, c4 = e % 400;
      float4 v = *(const float4*)(x + ((size_t)(n * kC + cg * 8 + r) * kTV + col0) + c4 * 4);
      *(float4*)&sm[r][c4 * 4] = v;
    }
    __syncthreads();
    for (int col = tid; col < 1600; col += 256) {
      union { u16 u[8]; uint4 v; } pk;
#pragma unroll
      for (int r = 0; r < 8; ++r) pk.u[r] = f2bf(sm[r][col]);
      *(uint4*)(xfn + (size_t)(cg * kTV + col0 + col) * 8) = pk.v;
    }
    for (int i = tid; i < 512; i += 256) {
      int c = i >> 6, tl = i & 63;
      float s = 0.f;
      const float* p = &sm[c][tl * 25];
#pragma unroll
      for (int j = 0; j < 25; ++j) s += p[j];
      xm[(size_t)(n * kC + cg * 8 + c) * kT + chunk * 64 + tl] = s * (1.0f / kV);
    }
    __syncthreads();
  }
}

// ---------- 2) thetaT/phiT [n][t][o] bf16 (k-contiguous for the f-MFMA) ----------
__global__ __launch_bounds__(256) void k_thetaphi(
    const float* __restrict__ xmean, const float* __restrict__ Wth, const float* __restrict__ bth,
    const float* __restrict__ Wph, const float* __restrict__ bph,
    u16* __restrict__ thT, u16* __restrict__ phT) {
  int n = blockIdx.x >> 5;
  int o0 = (blockIdx.x & 31) * 4;
  int t = threadIdx.x;
  __shared__ float wt[4][kC], wp[4][kC];
  for (int i = threadIdx.x; i < 1024; i += 256) {
    wt[i >> 8][i & 255] = Wth[(o0 + (i >> 8)) * kC + (i & 255)];
    wp[i >> 8][i & 255] = Wph[(o0 + (i >> 8)) * kC + (i & 255)];
  }
  __syncthreads();
  const float* xmp = xmean + (size_t)n * kC * kT + t;
  float a[4], p[4];
#pragma unroll
  for (int j = 0; j < 4; ++j) { a[j] = bth[o0 + j]; p[j] = bph[o0 + j]; }
#pragma unroll 4
  for (int c = 0; c < kC; ++c) {
    float xv = xmp[c * kT];
#pragma unroll
    for (int j = 0; j < 4; ++j) {
      a[j] = fmaf(wt[j][c], xv, a[j]);
      p[j] = fmaf(wp[j][c], xv, p[j]);
    }
  }
  size_t rowb = ((size_t)n * kT + t) * kCI + o0;
#pragma unroll
  for (int j = 0; j < 4; ++j) {
    thT[rowb + j] = f2bf(a[j]);
    phT[rowb + j] = f2bf(p[j]);
  }
}

// ---------- 3) f = softmax(theta^T phi); store A-frag-linear f_fl[n] ----------
__global__ __launch_bounds__(512) void k_fmfma(const u16* __restrict__ thT, const u16* __restrict__ phT,
                                               u16* __restrict__ f_fl) {
  const int n = blockIdx.x >> 1;
  const int tc0 = (blockIdx.x & 1) * 128;
  const int tid = threadIdx.x, lane = tid & 63, w = tid >> 6;
  const int wM = w & 3, wr = wM * 64, wc = (w >> 2) * 64;
  const int l15 = lane & 15, l4 = lane >> 4;
  __shared__ float redm[4][128], reds[4][128];
  f4v acc[4][4];
#pragma unroll
  for (int i = 0; i < 4; ++i)
#pragma unroll
    for (int j = 0; j < 4; ++j) acc[i][j] = f4v{0.f, 0.f, 0.f, 0.f};
#pragma unroll
  for (int ks = 0; ks < 4; ++ks) {
    s8v af[4], bf[4];
#pragma unroll
    for (int fi = 0; fi < 4; ++fi)
      af[fi] = *(const s8v*)(phT + ((size_t)(n * 256 + wr + fi * 16 + l15) * kCI + ks * 32 + l4 * 8));
#pragma unroll
    for (int g = 0; g < 4; ++g)
      bf[g] = *(const s8v*)(thT + ((size_t)(n * 256 + tc0 + wc + g * 16 + l15) * kCI + ks * 32 + l4 * 8));
#pragma unroll
    for (int g = 0; g < 4; ++g)
#pragma unroll
      for (int fi = 0; fi < 4; ++fi)
        acc[fi][g] = __builtin_amdgcn_mfma_f32_16x16x32_bf16(af[fi], bf[g], acc[fi][g], 0, 0, 0);
  }
  // D[r=t'][c=t]; softmax over t'
  float mx[4], sm[4];
#pragma unroll
  for (int g = 0; g < 4; ++g) {
    float m = -1e30f;
#pragma unroll
    for (int fi = 0; fi < 4; ++fi)
#pragma unroll
      for (int r = 0; r < 4; ++r) m = fmaxf(m, acc[fi][g][r]);
    m = fmaxf(m, __shfl_xor(m, 16));
    m = fmaxf(m, __shfl_xor(m, 32));
    mx[g] = m;
  }
  if (l4 == 0)
#pragma unroll
    for (int g = 0; g < 4; ++g) redm[wM][wc + g * 16 + l15] = mx[g];
  __syncthreads();
#pragma unroll
  for (int g = 0; g < 4; ++g) {
    int col = wc + g * 16 + l15;
    mx[g] = fmaxf(fmaxf(redm[0][col], redm[1][col]), fmaxf(redm[2][col], redm[3][col]));
  }
#pragma unroll
  for (int g = 0; g < 4; ++g) {
    float s = 0.f;
#pragma unroll
    for (int fi = 0; fi < 4; ++fi)
#pragma unroll
      for (int r = 0; r < 4; ++r) {
        float e = __expf(acc[fi][g][r] - mx[g]);
        acc[fi][g][r] = e;
        s += e;
      }
    s += __shfl_xor(s, 16);
    s += __shfl_xor(s, 32);
    sm[g] = s;
  }
  if (l4 == 0)
#pragma unroll
    for (int g = 0; g < 4; ++g) reds[wM][wc + g * 16 + l15] = sm[g];
  __syncthreads();
#pragma unroll
  for (int g = 0; g < 4; ++g) {
    int col = wc + g * 16 + l15;
    float inv = 1.0f / (reds[0][col] + reds[1][col] + reds[2][col] + reds[3][col]);
    int t = tc0 + col;
#pragma unroll
    for (int fi = 0; fi < 4; ++fi) {
      int tp0 = wr + fi * 16 + l4 * 4;  // t' base; tp0&7 in {0,4}
      ushort4 st;
      st.x = f2bf(acc[fi][g][0] * inv);
      st.y = f2bf(acc[fi][g][1] * inv);
      st.z = f2bf(acc[fi][g][2] * inv);
      st.w = f2bf(acc[fi][g][3] * inv);
      *(ushort4*)(f_fl + (size_t)n * 65536 + (size_t)((tp0 >> 3) * 256 + t) * 8 + (tp0 & 7)) = st;
    }
  }
}

// ---------- convert Wg, Ww to fragment-linear bf16 ----------
__global__ __launch_bounds__(256) void k_cvtW(const float* __restrict__ Wg, const float* __restrict__ Ww,
                                              u16* __restrict__ Wg_fl, u16* __restrict__ Ww_fl) {
  int i = blockIdx.x * 256 + threadIdx.x;  // 0..32767
  { int m = i >> 8, k = i & 255; Wg_fl[(size_t)((k >> 3) * 128 + m) * 8 + (k & 7)] = f2bf(Wg[i]); }
  { int m = i >> 7, k = i & 127; Ww_fl[(size_t)((k >> 3) * 256 + m) * 8 + (k & 7)] = f2bf(Ww[i]); }
}

// ---------- zero-LDS MFMA GEMM: C_n[128m x 128cols] = A @ B_n, all frag-direct ----------
// MODE 0: g    A=Wg_fl(M=128)      B=x_fl  (K=256,NC=6400) out g2_fl (+bias)
// MODE 1: attn A=f_fl[n](M=256)    B=g2_fl (K=256,NC=3200) out yb_rm + yb_fl
// MODE 2: wy   A=Ww_fl(M=256)      B=yb_fl (K=128,NC=6400) out f32 BN+residual(x f32)
template <int K_TOT, int NCOLS, int MODE>
__global__ __launch_bounds__(256) void k_gemm(
    const u16* __restrict__ A_, const u16* __restrict__ B_, const float* __restrict__ bias,
    void* __restrict__ outp, void* __restrict__ outp2, const float* __restrict__ scale,
    const float* __restrict__ shift, const float* __restrict__ xres) {
  constexpr int KSTEPS = K_TOT / 32;
  constexpr int M_TOT = (MODE == 0) ? 128 : 256;
  const int n = blockIdx.z, m0 = blockIdx.y * 128, n0 = blockIdx.x * 128;
  const int tid = threadIdx.x, lane = tid & 63, w = tid >> 6;
  const int wr = (w >> 1) * 64, wc = (w & 1) * 64;
  const int l15 = lane & 15, l4 = lane >> 4;
  const u16* Bn = B_ + (size_t)n * (K_TOT / 8) * NCOLS * 8;
  const u16* An = (MODE == 1) ? A_ + (size_t)n * 65536 : A_;
  f4v acc[4][4];
#pragma unroll
  for (int i = 0; i < 4; ++i)
#pragma unroll
    for (int j = 0; j < 4; ++j) acc[i][j] = f4v{0.f, 0.f, 0.f, 0.f};

#pragma unroll 2
  for (int ks = 0; ks < KSTEPS; ++ks) {
    const int ksub = ks * 4 + l4;
    s8v af[4], bf[4];
#pragma unroll
    for (int fi = 0; fi < 4; ++fi)
      af[fi] = *(const s8v*)(An + (size_t)(ksub * M_TOT + m0 + wr + fi * 16 + l15) * 8);
#pragma unroll
    for (int g = 0; g < 4; ++g)
      bf[g] = *(const s8v*)(Bn + (size_t)(ksub * NCOLS + n0 + wc + g * 16 + l15) * 8);
#pragma unroll
    for (int g = 0; g < 4; ++g)
#pragma unroll
      for (int fi = 0; fi < 4; ++fi)
        acc[fi][g] = __builtin_amdgcn_mfma_f32_16x16x32_bf16(af[fi], bf[g], acc[fi][g], 0, 0, 0);
  }
#pragma unroll
  for (int fi = 0; fi < 4; ++fi) {
    int growb = m0 + wr + fi * 16 + l4 * 4;
#pragma unroll
    for (int g = 0; g < 4; ++g) {
      int gcol = n0 + wc + g * 16 + l15;
#pragma unroll
      for (int r = 0; r < 4; ++r) {
        int grow = growb + r;
        float vv = acc[fi][g][r];
        if constexpr (MODE == 0) {
          vv += bias[grow];
          int t = gcol / 25, v5 = gcol - t * 25;
          ((u16*)outp)[(size_t)n * 819200 + (size_t)((t >> 3) * 3200 + grow * 25 + v5) * 8 + (t & 7)] = f2bf(vv);
        } else if constexpr (MODE == 1) {
          int ci = gcol / 25, v5 = gcol - ci * 25;
          u16 b = f2bf(vv);
          ((u16*)outp)[((size_t)n * kCI + ci) * kTV + grow * 25 + v5] = b;
          ((u16*)outp2)[(size_t)n * 819200 + (size_t)((ci >> 3) * 6400 + grow * 25 + v5) * 8 + (ci & 7)] = b;
        } else {
          size_t idx = ((size_t)n * kC + grow) * kTV + gcol;
          ((float*)outp)[idx] = vv * scale[grow] + shift[grow] + xres[idx];
        }
      }
    }
  }
}

// ---------- Syy = Y Y^T + Sy, MFMA, zero LDS (yb_rm rows k-contiguous) ----------
__global__ __launch_bounds__(256) void k_syy(const u16* __restrict__ yb, float* __restrict__ psyy,
                                             float* __restrict__ psy) {
  const int b = blockIdx.x, n = b >> 3, kc = b & 7;
  const int kbase = kc * 800;
  const int tid = threadIdx.x, lane = tid & 63, w = tid >> 6;
  const int wr = (w >> 1) * 64, wc = (w & 1) * 64, l15 = lane & 15, l4 = lane >> 4;
  const u16* Y = yb + (size_t)n * kCI * kTV;
  f4v acc[4][4];
#pragma unroll
  for (int i = 0; i < 4; ++i)
#pragma unroll
    for (int j = 0; j < 4; ++j) acc[i][j] = f4v{0.f, 0.f, 0.f, 0.f};
  float syl[4] = {0.f, 0.f, 0.f, 0.f};
  for (int ks = 0; ks < 25; ++ks) {
    int k = kbase + ks * 32 + l4 * 8;
    s8v af[4], bf[4];
#pragma unroll
    for (int fi = 0; fi < 4; ++fi) {
      af[fi] = *(const s8v*)(Y + (size_t)(wr + fi * 16 + l15) * kTV + k);
      bf[fi] = *(const s8v*)(Y + (size_t)(wc + fi * 16 + l15) * kTV + k);
    }
#pragma unroll
    for (int fi = 0; fi < 4; ++fi)
#pragma unroll
      for (int j = 0; j < 8; ++j) syl[fi] += bf2f((u16)af[fi][j]);
#pragma unroll
    for (int g = 0; g < 4; ++g)
#pragma unroll
      for (int fi = 0; fi < 4; ++fi)
        acc[fi][g] = __builtin_amdgcn_mfma_f32_16x16x32_bf16(af[fi], bf[g], acc[fi][g], 0, 0, 0);
  }
  float* pb = psyy + (size_t)b * 16384;
#pragma unroll
  for (int fi = 0; fi < 4; ++fi)
#pragma unroll
    for (int g = 0; g < 4; ++g)
#pragma unroll
      for (int r = 0; r < 4; ++r)
        pb[(wr + fi * 16 + l4 * 4 + r) * kCI + wc + g * 16 + l15] = acc[fi][g][r];
#pragma unroll
  for (int fi = 0; fi < 4; ++fi) {
    float s = syl[fi];
    s += __shfl_xor(s, 16);
    s += __shfl_xor(s, 32);
    if ((w & 1) == 0 && l4 == 0) psy[b * kCI + wr + fi * 16 + l15] = s;
  }
}

__global__ __launch_bounds__(256) void k_reduce(const float* __restrict__ psyy, const float* __restrict__ psy,
                                                float* __restrict__ syy, float* __restrict__ sy) {
  if (blockIdx.x < 64) {
    int i = blockIdx.x * 256 + threadIdx.x;
    float s = 0.f;
    for (int b = 0; b < SYY_B; ++b) s += psyy[(size_t)b * 16384 + i];
    syy[i] = s;
  } else if (threadIdx.x < kCI) {
    float s = 0.f;
    for (int b = 0; b < SYY_B; ++b) s += psy[b * kCI + threadIdx.x];
    sy[threadIdx.x] = s;
  }
}

__global__ __launch_bounds__(128) void k_stats(const float* __restrict__ syy, const float* __restrict__ sy,
                                               const float* __restrict__ Ww, const float* __restrict__ bw,
                                               const float* __restrict__ gamma, const float* __restrict__ beta,
                                               float* __restrict__ scale, float* __restrict__ shift) {
  int c2 = blockIdx.x;
  int tid = threadIdx.x;
  __shared__ float wsm[kCI];
  __shared__ float red1[kCI], red2[kCI];
  wsm[tid] = Ww[c2 * kCI + tid];
  __syncthreads();
  float val = 0.f;
#pragma unroll 8
  for (int ci = 0; ci < kCI; ++ci) val = fmaf(wsm[ci], syy[ci * kCI + tid], val);
  red1[tid] = wsm[tid] * sy[tid];
  red2[tid] = val * wsm[tid];
  __syncthreads();
  for (int s = 64; s > 0; s >>= 1) {
    if (tid < s) { red1[tid] += red1[tid + s]; red2[tid] += red2[tid + s]; }
    __syncthreads();
  }
  if (tid == 0) {
    const float invS = 1.0f / (float)kSAMP;
    float m1 = red1[0] * invS;
    float b = bw[c2];
    float mu = m1 + b;
    float e2 = red2[0] * invS + 2.f * b * m1 + b * b;
    float var = e2 - mu * mu;
    float rstd = rsqrtf(var + 1e-5f);
    float sc = rstd * gamma[c2];
    scale[c2] = sc;
    shift[c2] = beta[c2] + (b - mu) * sc;
  }
}

extern "C" void kernel_launch(void* const* d_in, const int* in_sizes, int n_in,
                              void* d_out, int out_size, void* d_ws, size_t ws_size,
                              hipStream_t stream) {
  const float* x     = (const float*)d_in[0];
  const float* Wg    = (const float*)d_in[1];
  const float* bg    = (const float*)d_in[2];
  const float* Wth   = (const float*)d_in[3];
  const float* bth   = (const float*)d_in[4];
  const float* Wph   = (const float*)d_in[5];
  const float* bph   = (const float*)d_in[6];
  const float* Ww    = (const float*)d_in[7];
  const float* bw    = (const float*)d_in[8];
  const float* gamma = (const float*)d_in[9];
  const float* beta  = (const float*)d_in[10];
  float* out = (float*)d_out;

  char* wsb = (char*)d_ws;
  float* xmean = (float*)(wsb);                    // 8 MB
  u16*   thT   = (u16*)(wsb + (8u << 20));         // 2 MB
  u16*   phT   = (u16*)(wsb + (10u << 20));        // 2 MB
  u16*   f_fl  = (u16*)(wsb + (12u << 20));        // 4 MB  A-frag-linear per n
  float* psy   = (float*)(wsb + (16u << 20));      // 128 KB
  float* syy   = (float*)(wsb + (17u << 20));      // 64 KB
  float* sy    = syy + 16384;
  float* scale = sy + 128;
  float* shift = scale + 256;
  u16* Wg_fl = (u16*)(wsb + (18u << 20));          // 64 KB
  u16* Ww_fl = Wg_fl + 32768;                      // 64 KB
  u16* x_fl  = (u16*)(wsb + (19u << 20));          // 100 MB (c-frag-linear)
  u16* yb_fl = x_fl;                               // aliases x_fl (dead after g-GEMM)
  u16* g2_fl = (u16*)(wsb + (119u << 20));         // 50 MB (t'-frag-linear)
  float* psyy = (float*)(wsb + (119u << 20));      // 16.8 MB, aliases g2_fl (dead after attn)
  u16* yb_rm = (u16*)(wsb + (169u << 20));         // 50 MB [N][CI][T*V]

  k_prep<<<1024, 256, 0, stream>>>(x, x_fl, xmean);
  k_cvtW<<<128, 256, 0, stream>>>(Wg, Ww, Wg_fl, Ww_fl);
  k_thetaphi<<<1024, 256, 0, stream>>>(xmean, Wth, bth, Wph, bph, thT, phT);
  k_fmfma<<<64, 512, 0, stream>>>(thT, phT, f_fl);
  k_gemm<256, kTV, 0><<<dim3(50, 1, 32), 256, 0, stream>>>(
      Wg_fl, x_fl, bg, (void*)g2_fl, nullptr, nullptr, nullptr, nullptr);
  k_gemm<256, 3200, 1><<<dim3(25, 2, 32), 256, 0, stream>>>(
      f_fl, g2_fl, nullptr, (void*)yb_rm, (void*)yb_fl, nullptr, nullptr, nullptr);
  k_syy<<<SYY_B, 256, 0, stream>>>(yb_rm, psyy, psy);
  k_reduce<<<65, 256, 0, stream>>>(psyy, psy, syy, sy);
  k_stats<<<256, 128, 0, stream>>>(syy, sy, Ww, bw, gamma, beta, scale, shift);
  k_gemm<128, kTV, 2><<<dim3(50, 2, 32), 256, 0, stream>>>(
      Ww_fl, yb_fl, nullptr, (void*)out, nullptr, scale, shift, x);
}

// Round 5
// 354.019 us; speedup vs baseline: 1.2717x; 1.2717x over previous
//
#include <hip/hip_runtime.h>

typedef unsigned short u16;
using s8v = __attribute__((ext_vector_type(8))) short;   // 8 x bf16 (4 VGPRs)
using f4v = __attribute__((ext_vector_type(4))) float;   // MFMA accumulator

constexpr int kN = 32, kC = 256, kT = 256, kV = 25, kCI = 128;
constexpr int kTV = kT * kV;        // 6400
constexpr int kCIV = kCI * kV;      // 3200
constexpr int kSAMP = kN * kT * kV; // 204800
constexpr int SYY_B = 256;          // 32 n * 8 chunks, 800 k each (1 block/CU)

__device__ __forceinline__ float bf2f(u16 v) {
  return __uint_as_float(((unsigned)v) << 16);
}
__device__ __forceinline__ u16 f2bf(float f) {
  unsigned u = __float_as_uint(f);
  return (u16)((u + 0x7FFFu + ((u >> 16) & 1u)) >> 16);
}

// ---------- 1) prep: x -> x_bf (bf16, same layout) + xmean over V ----------
__global__ __launch_bounds__(256) void k_prep(const float* __restrict__ x, u16* __restrict__ x_bf,
                                              float* __restrict__ xm) {
  __shared__ float sm[6400];
  size_t base = (size_t)blockIdx.x * 6400;
  const float4* src = (const float4*)(x + base);
  ushort4* dst = (ushort4*)(x_bf + base);
  for (int i = threadIdx.x; i < 1600; i += 256) {
    float4 v = src[i];
    ((float4*)sm)[i] = v;
    ushort4 b;
    b.x = f2bf(v.x); b.y = f2bf(v.y); b.z = f2bf(v.z); b.w = f2bf(v.w);
    dst[i] = b;
  }
  __syncthreads();
  const float* r = sm + threadIdx.x * 25;  // stride 25: gcd(25,32)=1
  float s = 0.f;
#pragma unroll
  for (int j = 0; j < 25; ++j) s += r[j];
  xm[(size_t)blockIdx.x * 256 + threadIdx.x] = s * (1.0f / kV);
}

// ---------- convert Wg, Ww, [Wth;Wph] to fragment-linear bf16 ----------
__global__ __launch_bounds__(256) void k_cvtW(const float* __restrict__ Wg, const float* __restrict__ Ww,
                                              const float* __restrict__ Wth, const float* __restrict__ Wph,
                                              u16* __restrict__ Wg_fl, u16* __restrict__ Ww_fl,
                                              u16* __restrict__ Wthph_fl) {
  int i = blockIdx.x * 256 + threadIdx.x;  // 0..32767
  { int m = i >> 8, k = i & 255; Wg_fl[(size_t)((k >> 3) * 128 + m) * 8 + (k & 7)] = f2bf(Wg[i]); }
  { int m = i >> 7, k = i & 127; Ww_fl[(size_t)((k >> 3) * 256 + m) * 8 + (k & 7)] = f2bf(Ww[i]); }
  { int m = i >> 8, k = i & 255;   // Wth -> rows 0..127, Wph -> rows 128..255 of combined M=256
    Wthph_fl[(size_t)((k >> 3) * 256 + m) * 8 + (k & 7)] = f2bf(Wth[i]);
    Wthph_fl[(size_t)((k >> 3) * 256 + (m + 128)) * 8 + (k & 7)] = f2bf(Wph[i]); }
}

// ---------- 2+3 fused) theta/phi (MFMA) + f = softmax(theta^T phi) (MFMA) ----------
// block = (n, tθ-half). LDS: phase1 xm_fl [16ksub][256t][8c] (c-half, 64KB);
// phase2+: th_l [16ksub(o)][128tθl][8o] 32KB @0, ph_l [16ksub(o)][256tφ][8o] 64KB @16384.
__global__ __launch_bounds__(512) void k_fattn(const float* __restrict__ xmean,
                                               const u16* __restrict__ Wthph_fl,
                                               const float* __restrict__ bth, const float* __restrict__ bph,
                                               u16* __restrict__ f) {
  __shared__ __align__(16) u16 lds[49152];  // 96 KB
  const int n = blockIdx.x >> 1, tc0 = (blockIdx.x & 1) * 128;
  const int tid = threadIdx.x, lane = tid & 63, w = tid >> 6;
  const int l15 = lane & 15, l4 = lane >> 4;
  // ---- phase 1: thph[o=256][t=256] = [Wth;Wph] @ xmean_n, waves 4 rows x 2 cols ----
  const int wro = (w & 3) * 64, wct = (w >> 2) * 128;
  f4v acc[4][8];
#pragma unroll
  for (int i = 0; i < 4; ++i)
#pragma unroll
    for (int j = 0; j < 8; ++j) acc[i][j] = f4v{0.f, 0.f, 0.f, 0.f};
  for (int ch = 0; ch < 2; ++ch) {
    __syncthreads();
    // stage xmean[n][ch*128+cc][t] -> xm_fl
    for (int e = tid; e < 8192; e += 512) {
      int cc = e >> 6, t4 = (e & 63) * 4;
      float4 v = *(const float4*)(xmean + (((size_t)(n * 256 + ch * 128 + cc)) << 8) + t4);
      u16* d = &lds[(((cc >> 3) * 256 + t4) << 3) + (cc & 7)];
      d[0] = f2bf(v.x); d[8] = f2bf(v.y); d[16] = f2bf(v.z); d[24] = f2bf(v.w);
    }
    __syncthreads();
#pragma unroll
    for (int ks = 0; ks < 4; ++ks) {
      const int ksub = ks * 4 + l4;  // 0..15 within half
      s8v af[4], bf[8];
#pragma unroll
      for (int fi = 0; fi < 4; ++fi)
        af[fi] = *(const s8v*)(Wthph_fl + (size_t)((ch * 16 + ksub) * 256 + wro + fi * 16 + l15) * 8);
#pragma unroll
      for (int g = 0; g < 8; ++g)
        bf[g] = *(const s8v*)&lds[((ksub * 256 + wct + g * 16 + l15) << 3)];
#pragma unroll
      for (int g = 0; g < 8; ++g)
#pragma unroll
        for (int fi = 0; fi < 4; ++fi)
          acc[fi][g] = __builtin_amdgcn_mfma_f32_16x16x32_bf16(af[fi], bf[g], acc[fi][g], 0, 0, 0);
    }
  }
  // ---- phase 2: +bias, store th_l (tθ-half cols only) / ph_l (all cols), frag-linear ----
  __syncthreads();
#pragma unroll
  for (int fi = 0; fi < 4; ++fi) {
    int o0 = wro + fi * 16 + l4 * 4;  // 4 consecutive rows o0..o0+3
    bool isTh = o0 < 128;
    float bb[4];
#pragma unroll
    for (int r = 0; r < 4; ++r) bb[r] = isTh ? bth[o0 + r] : bph[o0 - 128 + r];
#pragma unroll
    for (int g = 0; g < 8; ++g) {
      int t = wct + g * 16 + l15;
      ushort4 pk;
      pk.x = f2bf(acc[fi][g][0] + bb[0]);
      pk.y = f2bf(acc[fi][g][1] + bb[1]);
      pk.z = f2bf(acc[fi][g][2] + bb[2]);
      pk.w = f2bf(acc[fi][g][3] + bb[3]);
      if (isTh) {
        unsigned tl = (unsigned)(t - tc0);
        if (tl < 128u)
          *(ushort4*)&lds[(((o0 >> 3) * 128 + (int)tl) << 3) + (o0 & 7)] = pk;
      } else {
        int o = o0 - 128;
        *(ushort4*)&lds[16384 + (((o >> 3) * 256 + t) << 3) + (o & 7)] = pk;
      }
    }
  }
  __syncthreads();
  // ---- phase 3: D[tφ=256 rows][tθl=128 cols] = phi^T theta, waves 4 rows x 2 cols ----
  const int wr = (w & 3) * 64, wcc = (w >> 2) * 64;
  const int wM = w & 3;
  f4v facc[4][4];
#pragma unroll
  for (int i = 0; i < 4; ++i)
#pragma unroll
    for (int j = 0; j < 4; ++j) facc[i][j] = f4v{0.f, 0.f, 0.f, 0.f};
#pragma unroll
  for (int ks = 0; ks < 4; ++ks) {
    const int ksub = ks * 4 + l4;  // k = o, 16 ksubs
    s8v af[4], bf[4];
#pragma unroll
    for (int fi = 0; fi < 4; ++fi)
      af[fi] = *(const s8v*)&lds[16384 + ((ksub * 256 + wr + fi * 16 + l15) << 3)];
#pragma unroll
    for (int g = 0; g < 4; ++g)
      bf[g] = *(const s8v*)&lds[((ksub * 128 + wcc + g * 16 + l15) << 3)];
#pragma unroll
    for (int g = 0; g < 4; ++g)
#pragma unroll
      for (int fi = 0; fi < 4; ++fi)
        facc[fi][g] = __builtin_amdgcn_mfma_f32_16x16x32_bf16(af[fi], bf[g], facc[fi][g], 0, 0, 0);
  }
  __syncthreads();  // th_l/ph_l dead; redm/reds alias lds[0..)
  float* redm = (float*)lds;         // [4][128]
  float* reds = redm + 512;          // [4][128]
  // ---- phase 4: softmax over rows (tφ) ----
  float mx[4], sm[4];
#pragma unroll
  for (int g = 0; g < 4; ++g) {
    float m = -1e30f;
#pragma unroll
    for (int fi = 0; fi < 4; ++fi)
#pragma unroll
      for (int r = 0; r < 4; ++r) m = fmaxf(m, facc[fi][g][r]);
    m = fmaxf(m, __shfl_xor(m, 16));
    m = fmaxf(m, __shfl_xor(m, 32));
    mx[g] = m;
  }
  if (l4 == 0)
#pragma unroll
    for (int g = 0; g < 4; ++g) redm[wM * 128 + wcc + g * 16 + l15] = mx[g];
  __syncthreads();
#pragma unroll
  for (int g = 0; g < 4; ++g) {
    int col = wcc + g * 16 + l15;
    mx[g] = fmaxf(fmaxf(redm[col], redm[128 + col]), fmaxf(redm[256 + col], redm[384 + col]));
  }
#pragma unroll
  for (int g = 0; g < 4; ++g) {
    float s = 0.f;
#pragma unroll
    for (int fi = 0; fi < 4; ++fi)
#pragma unroll
      for (int r = 0; r < 4; ++r) {
        float e = __expf(facc[fi][g][r] - mx[g]);
        facc[fi][g][r] = e;
        s += e;
      }
    s += __shfl_xor(s, 16);
    s += __shfl_xor(s, 32);
    sm[g] = s;
  }
  if (l4 == 0)
#pragma unroll
    for (int g = 0; g < 4; ++g) reds[wM * 128 + wcc + g * 16 + l15] = sm[g];
  __syncthreads();
  // ---- phase 5: normalize + store f row-major [n][tθ][tφ] ----
#pragma unroll
  for (int g = 0; g < 4; ++g) {
    int col = wcc + g * 16 + l15;
    float inv = 1.0f / (reds[col] + reds[128 + col] + reds[256 + col] + reds[384 + col]);
    int t = tc0 + col;  // tθ global
#pragma unroll
    for (int fi = 0; fi < 4; ++fi) {
      int tp0 = wr + fi * 16 + l4 * 4;  // tφ base, 4 consecutive
      ushort4 st;
      st.x = f2bf(facc[fi][g][0] * inv);
      st.y = f2bf(facc[fi][g][1] * inv);
      st.z = f2bf(facc[fi][g][2] * inv);
      st.w = f2bf(facc[fi][g][3] * inv);
      *(ushort4*)(f + (size_t)(n * 256 + t) * 256 + tp0) = st;
    }
  }
}

// ---------- MFMA GEMM: C_n[M,128-tile] = A @ B_n (R3-proven LDS-gather form) ----------
// MODE 0: g    (A=Wg_fl M=128, B=x_bf stride 6400, +bias, out g2 [N][T][CI*V] bf16)
// MODE 1: attn (A=f row-major [n][256][256], B=g2 stride 3200, out yb [N][CI][T*V] bf16)
// MODE 2: wy   (A=Ww_fl M=256, B=yb stride 6400, BN+residual(bf16), out f32 [N][C][T*V])
template <int K_TOT, int NCOLS, int MODE>
__global__ __launch_bounds__(256) void k_gemm(
    const u16* __restrict__ A_, const u16* __restrict__ B_, const float* __restrict__ bias,
    void* __restrict__ outp, const float* __restrict__ scale, const float* __restrict__ shift,
    const u16* __restrict__ xres) {
  constexpr int KSTEPS = K_TOT / 32;
  constexpr int M_TOT = (MODE == 0) ? 128 : 256;
  __shared__ uint4 Bs[512];  // frag blocks [ksub][col] of 8 bf16, XOR-swizzled
  const int n = blockIdx.z, m0 = blockIdx.y * 128, n0 = blockIdx.x * 128;
  const int tid = threadIdx.x, lane = tid & 63, w = tid >> 6;
  const int wr = (w >> 1) * 64, wc = (w & 1) * 64;
  const int l15 = lane & 15, l4 = lane >> 4;
  const u16* Bn = B_ + (size_t)n * K_TOT * NCOLS + n0;
  const int scol = tid & 127, sk0 = tid >> 7;
  f4v acc[4][4];
#pragma unroll
  for (int i = 0; i < 4; ++i)
#pragma unroll
    for (int j = 0; j < 4; ++j) acc[i][j] = f4v{0.f, 0.f, 0.f, 0.f};

  for (int ks = 0; ks < KSTEPS; ++ks) {
    __syncthreads();
#pragma unroll
    for (int p = 0; p < 2; ++p) {
      int ksub = sk0 + p * 2;
      const u16* src = Bn + (size_t)(ks * 32 + ksub * 8) * NCOLS + scol;
      union { u16 u[8]; uint4 v; } pk;
#pragma unroll
      for (int j = 0; j < 8; ++j) pk.u[j] = src[(size_t)j * NCOLS];
      int blk = ksub * 128 + scol;
      blk ^= (blk >> 2) & 3;
      Bs[blk] = pk.v;
    }
    __syncthreads();
    s8v af[4];
#pragma unroll
    for (int fi = 0; fi < 4; ++fi) {
      int m = m0 + wr + fi * 16 + l15;
      const u16* ap;
      if constexpr (MODE == 1)
        ap = A_ + ((size_t)(n * 256 + m) * 256 + ks * 32 + l4 * 8);
      else
        ap = A_ + (size_t)((ks * 4 + l4) * M_TOT + m) * 8;
      af[fi] = *(const s8v*)ap;
    }
#pragma unroll
    for (int g = 0; g < 4; ++g) {
      int blk = l4 * 128 + wc + g * 16 + l15;
      blk ^= (blk >> 2) & 3;
      s8v bf = *(const s8v*)&Bs[blk];
#pragma unroll
      for (int fi = 0; fi < 4; ++fi)
        acc[fi][g] = __builtin_amdgcn_mfma_f32_16x16x32_bf16(af[fi], bf, acc[fi][g], 0, 0, 0);
    }
  }
#pragma unroll
  for (int fi = 0; fi < 4; ++fi) {
    int growb = m0 + wr + fi * 16 + l4 * 4;
#pragma unroll
    for (int g = 0; g < 4; ++g) {
      int gcol = n0 + wc + g * 16 + l15;
#pragma unroll
      for (int r = 0; r < 4; ++r) {
        int grow = growb + r;
        float vv = acc[fi][g][r];
        if constexpr (MODE == 0) {
          vv += bias[grow];
          int t = gcol / 25, v5 = gcol - t * 25;
          ((u16*)outp)[((size_t)n * kT + t) * kCIV + grow * 25 + v5] = f2bf(vv);
        } else if constexpr (MODE == 1) {
          int ci = gcol / 25, v5 = gcol - ci * 25;
          ((u16*)outp)[((size_t)n * kCI + ci) * kTV + grow * 25 + v5] = f2bf(vv);
        } else {
          size_t idx = ((size_t)n * kC + grow) * kTV + gcol;
          ((float*)outp)[idx] = vv * scale[grow] + shift[grow] + bf2f(xres[idx]);
        }
      }
    }
  }
}

// ---------- Syy = Y Y^T + Sy, MFMA, zero LDS (yb rows k-contiguous) ----------
__global__ __launch_bounds__(256) void k_syy(const u16* __restrict__ yb, float* __restrict__ psyy,
                                             float* __restrict__ psy) {
  const int b = blockIdx.x, n = b >> 3, kc = b & 7;
  const int kbase = kc * 800;
  const int tid = threadIdx.x, lane = tid & 63, w = tid >> 6;
  const int wr = (w >> 1) * 64, wc = (w & 1) * 64, l15 = lane & 15, l4 = lane >> 4;
  const u16* Y = yb + (size_t)n * kCI * kTV;
  f4v acc[4][4];
#pragma unroll
  for (int i = 0; i < 4; ++i)
#pragma unroll
    for (int j = 0; j < 4; ++j) acc[i][j] = f4v{0.f, 0.f, 0.f, 0.f};
  float syl[4] = {0.f, 0.f, 0.f, 0.f};
  for (int ks = 0; ks < 25; ++ks) {
    int k = kbase + ks * 32 + l4 * 8;
    s8v af[4], bf[4];
#pragma unroll
    for (int fi = 0; fi < 4; ++fi) {
      af[fi] = *(const s8v*)(Y + (size_t)(wr + fi * 16 + l15) * kTV + k);
      bf[fi] = *(const s8v*)(Y + (size_t)(wc + fi * 16 + l15) * kTV + k);
    }
#pragma unroll
    for (int fi = 0; fi < 4; ++fi)
#pragma unroll
      for (int j = 0; j < 8; ++j) syl[fi] += bf2f((u16)af[fi][j]);
#pragma unroll
    for (int g = 0; g < 4; ++g)
#pragma unroll
      for (int fi = 0; fi < 4; ++fi)
        acc[fi][g] = __builtin_amdgcn_mfma_f32_16x16x32_bf16(af[fi], bf[g], acc[fi][g], 0, 0, 0);
  }
  float* pb = psyy + (size_t)b * 16384;
#pragma unroll
  for (int fi = 0; fi < 4; ++fi)
#pragma unroll
    for (int g = 0; g < 4; ++g)
#pragma unroll
      for (int r = 0; r < 4; ++r)
        pb[(wr + fi * 16 + l4 * 4 + r) * kCI + wc + g * 16 + l15] = acc[fi][g][r];
#pragma unroll
  for (int fi = 0; fi < 4; ++fi) {
    float s = syl[fi];
    s += __shfl_xor(s, 16);
    s += __shfl_xor(s, 32);
    if ((w & 1) == 0 && l4 == 0) psy[b * kCI + wr + fi * 16 + l15] = s;
  }
}

__global__ __launch_bounds__(256) void k_reduce(const float* __restrict__ psyy, const float* __restrict__ psy,
                                                float* __restrict__ syy, float* __restrict__ sy) {
  if (blockIdx.x < 64) {
    int i = blockIdx.x * 256 + threadIdx.x;
    float s = 0.f;
    for (int b = 0; b < SYY_B; ++b) s += psyy[(size_t)b * 16384 + i];
    syy[i] = s;
  } else if (threadIdx.x < kCI) {
    float s = 0.f;
    for (int b = 0; b < SYY_B; ++b) s += psy[b * kCI + threadIdx.x];
    sy[threadIdx.x] = s;
  }
}

__global__ __launch_bounds__(128) void k_stats(const float* __restrict__ syy, const float* __restrict__ sy,
                                               const float* __restrict__ Ww, const float* __restrict__ bw,
                                               const float* __restrict__ gamma, const float* __restrict__ beta,
                                               float* __restrict__ scale, float* __restrict__ shift) {
  int c2 = blockIdx.x;
  int tid = threadIdx.x;
  __shared__ float wsm[kCI];
  __shared__ float red1[kCI], red2[kCI];
  wsm[tid] = Ww[c2 * kCI + tid];
  __syncthreads();
  float val = 0.f;
#pragma unroll 8
  for (int ci = 0; ci < kCI; ++ci) val = fmaf(wsm[ci], syy[ci * kCI + tid], val);
  red1[tid] = wsm[tid] * sy[tid];
  red2[tid] = val * wsm[tid];
  __syncthreads();
  for (int s = 64; s > 0; s >>= 1) {
    if (tid < s) { red1[tid] += red1[tid + s]; red2[tid] += red2[tid + s]; }
    __syncthreads();
  }
  if (tid == 0) {
    const float invS = 1.0f / (float)kSAMP;
    float m1 = red1[0] * invS;
    float b = bw[c2];
    float mu = m1 + b;
    float e2 = red2[0] * invS + 2.f * b * m1 + b * b;
    float var = e2 - mu * mu;
    float rstd = rsqrtf(var + 1e-5f);
    float sc = rstd * gamma[c2];
    scale[c2] = sc;
    shift[c2] = beta[c2] + (b - mu) * sc;
  }
}

extern "C" void kernel_launch(void* const* d_in, const int* in_sizes, int n_in,
                              void* d_out, int out_size, void* d_ws, size_t ws_size,
                              hipStream_t stream) {
  const float* x     = (const float*)d_in[0];
  const float* Wg    = (const float*)d_in[1];
  const float* bg    = (const float*)d_in[2];
  const float* Wth   = (const float*)d_in[3];
  const float* bth   = (const float*)d_in[4];
  const float* Wph   = (const float*)d_in[5];
  const float* bph   = (const float*)d_in[6];
  const float* Ww    = (const float*)d_in[7];
  const float* bw    = (const float*)d_in[8];
  const float* gamma = (const float*)d_in[9];
  const float* beta  = (const float*)d_in[10];
  float* out = (float*)d_out;

  char* wsb = (char*)d_ws;
  float* xmean = (float*)(wsb);                    // 8 MB
  u16* Wthph_fl = (u16*)(wsb + (8u << 20));        // 128 KB
  u16*   f_bf  = (u16*)(wsb + (12u << 20));        // 4 MB  [n][tθ][tφ] bf16 row-major
  float* psy   = (float*)(wsb + (16u << 20));      // 128 KB
  float* syy   = (float*)(wsb + (17u << 20));      // 64 KB
  float* sy    = syy + 16384;
  float* scale = sy + 128;
  float* shift = scale + 256;
  u16* Wg_fl = (u16*)(wsb + (18u << 20));          // 64 KB
  u16* Ww_fl = Wg_fl + 32768;                      // 64 KB
  u16* x_bf  = (u16*)(wsb + (19u << 20));          // 100 MB [n][c][t*v] bf16 linear
  u16* g2    = (u16*)(wsb + (119u << 20));         // 50 MB [N][T][CI*V] bf16
  float* psyy = (float*)(wsb + (119u << 20));      // 16.8 MB, aliases g2 (dead after attn)
  u16* yb    = (u16*)(wsb + (172u << 20));         // 50 MB [N][CI][T*V] bf16

  k_cvtW<<<128, 256, 0, stream>>>(Wg, Ww, Wth, Wph, Wg_fl, Ww_fl, Wthph_fl);
  k_prep<<<8192, 256, 0, stream>>>(x, x_bf, xmean);
  k_fattn<<<64, 512, 0, stream>>>(xmean, Wthph_fl, bth, bph, f_bf);
  k_gemm<256, kTV, 0><<<dim3(50, 1, 32), 256, 0, stream>>>(
      Wg_fl, x_bf, bg, (void*)g2, nullptr, nullptr, nullptr);
  k_gemm<256, kCIV, 1><<<dim3(25, 2, 32), 256, 0, stream>>>(
      f_bf, g2, nullptr, (void*)yb, nullptr, nullptr, nullptr);
  k_syy<<<SYY_B, 256, 0, stream>>>(yb, psyy, psy);
  k_reduce<<<65, 256, 0, stream>>>(psyy, psy, syy, sy);
  k_stats<<<256, 128, 0, stream>>>(syy, sy, Ww, bw, gamma, beta, scale, shift);
  k_gemm<128, kTV, 2><<<dim3(50, 2, 32), 256, 0, stream>>>(
      Ww_fl, yb, nullptr, (void*)out, scale, shift, x_bf);
}

// Round 6
// 351.958 us; speedup vs baseline: 1.2791x; 1.0059x over previous
//
#include <hip/hip_runtime.h>

typedef unsigned short u16;
using s8v = __attribute__((ext_vector_type(8))) short;   // 8 x bf16 (4 VGPRs)
using f4v = __attribute__((ext_vector_type(4))) float;   // MFMA accumulator

constexpr int kN = 32, kC = 256, kT = 256, kV = 25, kCI = 128;
constexpr int kTV = kT * kV;        // 6400
constexpr int kCIV = kCI * kV;      // 3200
constexpr int kSAMP = kN * kT * kV; // 204800
constexpr int SYY_B = 256;          // 32 n * 8 chunks, 800 k each (1 block/CU)

__device__ __forceinline__ float bf2f(u16 v) {
  return __uint_as_float(((unsigned)v) << 16);
}
__device__ __forceinline__ u16 f2bf(float f) {
  unsigned u = __float_as_uint(f);
  return (u16)((u + 0x7FFFu + ((u >> 16) & 1u)) >> 16);
}

// ---------- 1) prep: x -> x_bf (bf16, same layout) + xmean over V ----------
__global__ __launch_bounds__(256) void k_prep(const float* __restrict__ x, u16* __restrict__ x_bf,
                                              float* __restrict__ xm) {
  __shared__ float sm[6400];
  size_t base = (size_t)blockIdx.x * 6400;
  const float4* src = (const float4*)(x + base);
  ushort4* dst = (ushort4*)(x_bf + base);
  for (int i = threadIdx.x; i < 1600; i += 256) {
    float4 v = src[i];
    ((float4*)sm)[i] = v;
    ushort4 b;
    b.x = f2bf(v.x); b.y = f2bf(v.y); b.z = f2bf(v.z); b.w = f2bf(v.w);
    dst[i] = b;
  }
  __syncthreads();
  const float* r = sm + threadIdx.x * 25;  // stride 25: gcd(25,32)=1
  float s = 0.f;
#pragma unroll
  for (int j = 0; j < 25; ++j) s += r[j];
  xm[(size_t)blockIdx.x * 256 + threadIdx.x] = s * (1.0f / kV);
}

// ---------- convert Wg, Ww, [Wth;Wph] to fragment-linear bf16 ----------
__global__ __launch_bounds__(256) void k_cvtW(const float* __restrict__ Wg, const float* __restrict__ Ww,
                                              const float* __restrict__ Wth, const float* __restrict__ Wph,
                                              u16* __restrict__ Wg_fl, u16* __restrict__ Ww_fl,
                                              u16* __restrict__ Wthph_fl) {
  int i = blockIdx.x * 256 + threadIdx.x;  // 0..32767
  { int m = i >> 8, k = i & 255; Wg_fl[(size_t)((k >> 3) * 128 + m) * 8 + (k & 7)] = f2bf(Wg[i]); }
  { int m = i >> 7, k = i & 127; Ww_fl[(size_t)((k >> 3) * 256 + m) * 8 + (k & 7)] = f2bf(Ww[i]); }
  { int m = i >> 8, k = i & 255;   // Wth -> rows 0..127, Wph -> rows 128..255 of combined M=256
    Wthph_fl[(size_t)((k >> 3) * 256 + m) * 8 + (k & 7)] = f2bf(Wth[i]);
    Wthph_fl[(size_t)((k >> 3) * 256 + (m + 128)) * 8 + (k & 7)] = f2bf(Wph[i]); }
}

// ---------- 2+3 fused) theta/phi (MFMA) + f = softmax(theta^T phi) (MFMA) ----------
__global__ __launch_bounds__(512) void k_fattn(const float* __restrict__ xmean,
                                               const u16* __restrict__ Wthph_fl,
                                               const float* __restrict__ bth, const float* __restrict__ bph,
                                               u16* __restrict__ f) {
  __shared__ __align__(16) u16 lds[49152];  // 96 KB
  const int n = blockIdx.x >> 1, tc0 = (blockIdx.x & 1) * 128;
  const int tid = threadIdx.x, lane = tid & 63, w = tid >> 6;
  const int l15 = lane & 15, l4 = lane >> 4;
  // ---- phase 1: thph[o=256][t=256] = [Wth;Wph] @ xmean_n ----
  const int wro = (w & 3) * 64, wct = (w >> 2) * 128;
  f4v acc[4][8];
#pragma unroll
  for (int i = 0; i < 4; ++i)
#pragma unroll
    for (int j = 0; j < 8; ++j) acc[i][j] = f4v{0.f, 0.f, 0.f, 0.f};
  for (int ch = 0; ch < 2; ++ch) {
    __syncthreads();
    for (int e = tid; e < 8192; e += 512) {
      int cc = e >> 6, t4 = (e & 63) * 4;
      float4 v = *(const float4*)(xmean + (((size_t)(n * 256 + ch * 128 + cc)) << 8) + t4);
      u16* d = &lds[(((cc >> 3) * 256 + t4) << 3) + (cc & 7)];
      d[0] = f2bf(v.x); d[8] = f2bf(v.y); d[16] = f2bf(v.z); d[24] = f2bf(v.w);
    }
    __syncthreads();
#pragma unroll
    for (int ks = 0; ks < 4; ++ks) {
      const int ksub = ks * 4 + l4;
      s8v af[4], bf[8];
#pragma unroll
      for (int fi = 0; fi < 4; ++fi)
        af[fi] = *(const s8v*)(Wthph_fl + (size_t)((ch * 16 + ksub) * 256 + wro + fi * 16 + l15) * 8);
#pragma unroll
      for (int g = 0; g < 8; ++g)
        bf[g] = *(const s8v*)&lds[((ksub * 256 + wct + g * 16 + l15) << 3)];
#pragma unroll
      for (int g = 0; g < 8; ++g)
#pragma unroll
        for (int fi = 0; fi < 4; ++fi)
          acc[fi][g] = __builtin_amdgcn_mfma_f32_16x16x32_bf16(af[fi], bf[g], acc[fi][g], 0, 0, 0);
    }
  }
  // ---- phase 2: +bias, store th_l / ph_l frag-linear ----
  __syncthreads();
#pragma unroll
  for (int fi = 0; fi < 4; ++fi) {
    int o0 = wro + fi * 16 + l4 * 4;
    bool isTh = o0 < 128;
    float bb[4];
#pragma unroll
    for (int r = 0; r < 4; ++r) bb[r] = isTh ? bth[o0 + r] : bph[o0 - 128 + r];
#pragma unroll
    for (int g = 0; g < 8; ++g) {
      int t = wct + g * 16 + l15;
      ushort4 pk;
      pk.x = f2bf(acc[fi][g][0] + bb[0]);
      pk.y = f2bf(acc[fi][g][1] + bb[1]);
      pk.z = f2bf(acc[fi][g][2] + bb[2]);
      pk.w = f2bf(acc[fi][g][3] + bb[3]);
      if (isTh) {
        unsigned tl = (unsigned)(t - tc0);
        if (tl < 128u)
          *(ushort4*)&lds[(((o0 >> 3) * 128 + (int)tl) << 3) + (o0 & 7)] = pk;
      } else {
        int o = o0 - 128;
        *(ushort4*)&lds[16384 + (((o >> 3) * 256 + t) << 3) + (o & 7)] = pk;
      }
    }
  }
  __syncthreads();
  // ---- phase 3: D[tφ][tθl] = phi^T theta ----
  const int wr = (w & 3) * 64, wcc = (w >> 2) * 64;
  const int wM = w & 3;
  f4v facc[4][4];
#pragma unroll
  for (int i = 0; i < 4; ++i)
#pragma unroll
    for (int j = 0; j < 4; ++j) facc[i][j] = f4v{0.f, 0.f, 0.f, 0.f};
#pragma unroll
  for (int ks = 0; ks < 4; ++ks) {
    const int ksub = ks * 4 + l4;
    s8v af[4], bf[4];
#pragma unroll
    for (int fi = 0; fi < 4; ++fi)
      af[fi] = *(const s8v*)&lds[16384 + ((ksub * 256 + wr + fi * 16 + l15) << 3)];
#pragma unroll
    for (int g = 0; g < 4; ++g)
      bf[g] = *(const s8v*)&lds[((ksub * 128 + wcc + g * 16 + l15) << 3)];
#pragma unroll
    for (int g = 0; g < 4; ++g)
#pragma unroll
      for (int fi = 0; fi < 4; ++fi)
        facc[fi][g] = __builtin_amdgcn_mfma_f32_16x16x32_bf16(af[fi], bf[g], facc[fi][g], 0, 0, 0);
  }
  __syncthreads();
  float* redm = (float*)lds;
  float* reds = redm + 512;
  // ---- phase 4: softmax over rows (tφ) ----
  float mx[4], sm[4];
#pragma unroll
  for (int g = 0; g < 4; ++g) {
    float m = -1e30f;
#pragma unroll
    for (int fi = 0; fi < 4; ++fi)
#pragma unroll
      for (int r = 0; r < 4; ++r) m = fmaxf(m, facc[fi][g][r]);
    m = fmaxf(m, __shfl_xor(m, 16));
    m = fmaxf(m, __shfl_xor(m, 32));
    mx[g] = m;
  }
  if (l4 == 0)
#pragma unroll
    for (int g = 0; g < 4; ++g) redm[wM * 128 + wcc + g * 16 + l15] = mx[g];
  __syncthreads();
#pragma unroll
  for (int g = 0; g < 4; ++g) {
    int col = wcc + g * 16 + l15;
    mx[g] = fmaxf(fmaxf(redm[col], redm[128 + col]), fmaxf(redm[256 + col], redm[384 + col]));
  }
#pragma unroll
  for (int g = 0; g < 4; ++g) {
    float s = 0.f;
#pragma unroll
    for (int fi = 0; fi < 4; ++fi)
#pragma unroll
      for (int r = 0; r < 4; ++r) {
        float e = __expf(facc[fi][g][r] - mx[g]);
        facc[fi][g][r] = e;
        s += e;
      }
    s += __shfl_xor(s, 16);
    s += __shfl_xor(s, 32);
    sm[g] = s;
  }
  if (l4 == 0)
#pragma unroll
    for (int g = 0; g < 4; ++g) reds[wM * 128 + wcc + g * 16 + l15] = sm[g];
  __syncthreads();
  // ---- phase 5: normalize + store f row-major [n][tθ][tφ] ----
#pragma unroll
  for (int g = 0; g < 4; ++g) {
    int col = wcc + g * 16 + l15;
    float inv = 1.0f / (reds[col] + reds[128 + col] + reds[256 + col] + reds[384 + col]);
    int t = tc0 + col;
#pragma unroll
    for (int fi = 0; fi < 4; ++fi) {
      int tp0 = wr + fi * 16 + l4 * 4;
      ushort4 st;
      st.x = f2bf(facc[fi][g][0] * inv);
      st.y = f2bf(facc[fi][g][1] * inv);
      st.z = f2bf(facc[fi][g][2] * inv);
      st.w = f2bf(facc[fi][g][3] * inv);
      *(ushort4*)(f + (size_t)(n * 256 + t) * 256 + tp0) = st;
    }
  }
}

// ---------- MFMA GEMM: C_n[BM x 128-tile] = A @ B_n (LDS-gather form) ----------
// NT=256 -> BM=128 (4 waves 2m x 2n); NT=512 -> BM=256 (8 waves 4m x 2n)
// MODE 0: g    (A=Wg_fl M=128, B=x_bf stride 6400, +bias, out g2 [N][T][CI*V] bf16)
// MODE 1: attn (A=f row-major [n][256][256], B=g2 stride 3200, out yb [N][CI][T*V] bf16)
// MODE 2: wy   (A=Ww_fl M=256, B=yb stride 6400, BN+residual(bf16), out f32 [N][C][T*V])
template <int K_TOT, int NCOLS, int MODE, int NT>
__global__ __launch_bounds__(NT) void k_gemm(
    const u16* __restrict__ A_, const u16* __restrict__ B_, const float* __restrict__ bias,
    void* __restrict__ outp, const float* __restrict__ scale, const float* __restrict__ shift,
    const u16* __restrict__ xres) {
  constexpr int KSTEPS = K_TOT / 32;
  constexpr int M_TOT = (MODE == 0) ? 128 : 256;
  __shared__ uint4 Bs[512];  // frag blocks [ksub][col] of 8 bf16, XOR-swizzled
  const int n = blockIdx.z, m0 = blockIdx.y * ((NT == 512) ? 256 : 128), n0 = blockIdx.x * 128;
  const int tid = threadIdx.x, lane = tid & 63, w = tid >> 6;
  const int wr = (w >> 1) * 64, wc = (w & 1) * 64;
  const int l15 = lane & 15, l4 = lane >> 4;
  const u16* Bn = B_ + (size_t)n * K_TOT * NCOLS + n0;
  const int scol = tid & 127, sk0 = tid >> 7;
  f4v acc[4][4];
#pragma unroll
  for (int i = 0; i < 4; ++i)
#pragma unroll
    for (int j = 0; j < 4; ++j) acc[i][j] = f4v{0.f, 0.f, 0.f, 0.f};

  for (int ks = 0; ks < KSTEPS; ++ks) {
    __syncthreads();
#pragma unroll
    for (int p = 0; p < 512 / NT; ++p) {
      int ksub = sk0 + p * (NT / 128);
      const u16* src = Bn + (size_t)(ks * 32 + ksub * 8) * NCOLS + scol;
      union { u16 u[8]; uint4 v; } pk;
#pragma unroll
      for (int j = 0; j < 8; ++j) pk.u[j] = src[(size_t)j * NCOLS];
      int blk = ksub * 128 + scol;
      blk ^= (blk >> 2) & 3;
      Bs[blk] = pk.v;
    }
    __syncthreads();
    s8v af[4];
#pragma unroll
    for (int fi = 0; fi < 4; ++fi) {
      int m = m0 + wr + fi * 16 + l15;
      const u16* ap;
      if constexpr (MODE == 1)
        ap = A_ + ((size_t)(n * 256 + m) * 256 + ks * 32 + l4 * 8);
      else
        ap = A_ + (size_t)((ks * 4 + l4) * M_TOT + m) * 8;
      af[fi] = *(const s8v*)ap;
    }
#pragma unroll
    for (int g = 0; g < 4; ++g) {
      int blk = l4 * 128 + wc + g * 16 + l15;
      blk ^= (blk >> 2) & 3;
      s8v bf = *(const s8v*)&Bs[blk];
#pragma unroll
      for (int fi = 0; fi < 4; ++fi)
        acc[fi][g] = __builtin_amdgcn_mfma_f32_16x16x32_bf16(af[fi], bf, acc[fi][g], 0, 0, 0);
    }
  }
#pragma unroll
  for (int fi = 0; fi < 4; ++fi) {
    int growb = m0 + wr + fi * 16 + l4 * 4;
#pragma unroll
    for (int g = 0; g < 4; ++g) {
      int gcol = n0 + wc + g * 16 + l15;
#pragma unroll
      for (int r = 0; r < 4; ++r) {
        int grow = growb + r;
        float vv = acc[fi][g][r];
        if constexpr (MODE == 0) {
          vv += bias[grow];
          int t = gcol / 25, v5 = gcol - t * 25;
          ((u16*)outp)[((size_t)n * kT + t) * kCIV + grow * 25 + v5] = f2bf(vv);
        } else if constexpr (MODE == 1) {
          int ci = gcol / 25, v5 = gcol - ci * 25;
          ((u16*)outp)[((size_t)n * kCI + ci) * kTV + grow * 25 + v5] = f2bf(vv);
        } else {
          size_t idx = ((size_t)n * kC + grow) * kTV + gcol;
          ((float*)outp)[idx] = vv * scale[grow] + shift[grow] + bf2f(xres[idx]);
        }
      }
    }
  }
}

// ---------- Syy = Y Y^T + Sy, MFMA, zero LDS (yb rows k-contiguous) ----------
__global__ __launch_bounds__(256) void k_syy(const u16* __restrict__ yb, float* __restrict__ psyy,
                                             float* __restrict__ psy) {
  const int b = blockIdx.x, n = b >> 3, kc = b & 7;
  const int kbase = kc * 800;
  const int tid = threadIdx.x, lane = tid & 63, w = tid >> 6;
  const int wr = (w >> 1) * 64, wc = (w & 1) * 64, l15 = lane & 15, l4 = lane >> 4;
  const u16* Y = yb + (size_t)n * kCI * kTV;
  f4v acc[4][4];
#pragma unroll
  for (int i = 0; i < 4; ++i)
#pragma unroll
    for (int j = 0; j < 4; ++j) acc[i][j] = f4v{0.f, 0.f, 0.f, 0.f};
  float syl[4] = {0.f, 0.f, 0.f, 0.f};
  for (int ks = 0; ks < 25; ++ks) {
    int k = kbase + ks * 32 + l4 * 8;
    s8v af[4], bf[4];
#pragma unroll
    for (int fi = 0; fi < 4; ++fi) {
      af[fi] = *(const s8v*)(Y + (size_t)(wr + fi * 16 + l15) * kTV + k);
      bf[fi] = *(const s8v*)(Y + (size_t)(wc + fi * 16 + l15) * kTV + k);
    }
#pragma unroll
    for (int fi = 0; fi < 4; ++fi)
#pragma unroll
      for (int j = 0; j < 8; ++j) syl[fi] += bf2f((u16)af[fi][j]);
#pragma unroll
    for (int g = 0; g < 4; ++g)
#pragma unroll
      for (int fi = 0; fi < 4; ++fi)
        acc[fi][g] = __builtin_amdgcn_mfma_f32_16x16x32_bf16(af[fi], bf[g], acc[fi][g], 0, 0, 0);
  }
  float* pb = psyy + (size_t)b * 16384;
#pragma unroll
  for (int fi = 0; fi < 4; ++fi)
#pragma unroll
    for (int g = 0; g < 4; ++g)
#pragma unroll
      for (int r = 0; r < 4; ++r)
        pb[(wr + fi * 16 + l4 * 4 + r) * kCI + wc + g * 16 + l15] = acc[fi][g][r];
#pragma unroll
  for (int fi = 0; fi < 4; ++fi) {
    float s = syl[fi];
    s += __shfl_xor(s, 16);
    s += __shfl_xor(s, 32);
    if ((w & 1) == 0 && l4 == 0) psy[b * kCI + wr + fi * 16 + l15] = s;
  }
}

__global__ __launch_bounds__(256) void k_reduce(const float* __restrict__ psyy, const float* __restrict__ psy,
                                                float* __restrict__ syy, float* __restrict__ sy) {
  if (blockIdx.x < 64) {
    int i = blockIdx.x * 256 + threadIdx.x;
    float s = 0.f;
    for (int b = 0; b < SYY_B; ++b) s += psyy[(size_t)b * 16384 + i];
    syy[i] = s;
  } else if (threadIdx.x < kCI) {
    float s = 0.f;
    for (int b = 0; b < SYY_B; ++b) s += psy[b * kCI + threadIdx.x];
    sy[threadIdx.x] = s;
  }
}

__global__ __launch_bounds__(128) void k_stats(const float* __restrict__ syy, const float* __restrict__ sy,
                                               const float* __restrict__ Ww, const float* __restrict__ bw,
                                               const float* __restrict__ gamma, const float* __restrict__ beta,
                                               float* __restrict__ scale, float* __restrict__ shift) {
  int c2 = blockIdx.x;
  int tid = threadIdx.x;
  __shared__ float wsm[kCI];
  __shared__ float red1[kCI], red2[kCI];
  wsm[tid] = Ww[c2 * kCI + tid];
  __syncthreads();
  float val = 0.f;
#pragma unroll 8
  for (int ci = 0; ci < kCI; ++ci) val = fmaf(wsm[ci], syy[ci * kCI + tid], val);
  red1[tid] = wsm[tid] * sy[tid];
  red2[tid] = val * wsm[tid];
  __syncthreads();
  for (int s = 64; s > 0; s >>= 1) {
    if (tid < s) { red1[tid] += red1[tid + s]; red2[tid] += red2[tid + s]; }
    __syncthreads();
  }
  if (tid == 0) {
    const float invS = 1.0f / (float)kSAMP;
    float m1 = red1[0] * invS;
    float b = bw[c2];
    float mu = m1 + b;
    float e2 = red2[0] * invS + 2.f * b * m1 + b * b;
    float var = e2 - mu * mu;
    float rstd = rsqrtf(var + 1e-5f);
    float sc = rstd * gamma[c2];
    scale[c2] = sc;
    shift[c2] = beta[c2] + (b - mu) * sc;
  }
}

extern "C" void kernel_launch(void* const* d_in, const int* in_sizes, int n_in,
                              void* d_out, int out_size, void* d_ws, size_t ws_size,
                              hipStream_t stream) {
  const float* x     = (const float*)d_in[0];
  const float* Wg    = (const float*)d_in[1];
  const float* bg    = (const float*)d_in[2];
  const float* Wth   = (const float*)d_in[3];
  const float* bth   = (const float*)d_in[4];
  const float* Wph   = (const float*)d_in[5];
  const float* bph   = (const float*)d_in[6];
  const float* Ww    = (const float*)d_in[7];
  const float* bw    = (const float*)d_in[8];
  const float* gamma = (const float*)d_in[9];
  const float* beta  = (const float*)d_in[10];
  float* out = (float*)d_out;

  char* wsb = (char*)d_ws;
  float* xmean = (float*)(wsb);                    // 8 MB
  u16* Wthph_fl = (u16*)(wsb + (8u << 20));        // 128 KB
  u16*   f_bf  = (u16*)(wsb + (12u << 20));        // 4 MB  [n][tθ][tφ] bf16 row-major
  float* psy   = (float*)(wsb + (16u << 20));      // 128 KB
  float* syy   = (float*)(wsb + (17u << 20));      // 64 KB
  float* sy    = syy + 16384;
  float* scale = sy + 128;
  float* shift = scale + 256;
  u16* Wg_fl = (u16*)(wsb + (18u << 20));          // 64 KB
  u16* Ww_fl = Wg_fl + 32768;                      // 64 KB
  u16* x_bf  = (u16*)(wsb + (19u << 20));          // 100 MB [n][c][t*v] bf16 linear
  u16* g2    = (u16*)(wsb + (119u << 20));         // 50 MB [N][T][CI*V] bf16
  float* psyy = (float*)(wsb + (119u << 20));      // 16.8 MB, aliases g2 (dead after attn)
  u16* yb    = (u16*)(wsb + (172u << 20));         // 50 MB [N][CI][T*V] bf16

  k_cvtW<<<128, 256, 0, stream>>>(Wg, Ww, Wth, Wph, Wg_fl, Ww_fl, Wthph_fl);
  k_prep<<<8192, 256, 0, stream>>>(x, x_bf, xmean);
  k_fattn<<<64, 512, 0, stream>>>(xmean, Wthph_fl, bth, bph, f_bf);
  k_gemm<256, kTV, 0, 256><<<dim3(50, 1, 32), 256, 0, stream>>>(
      Wg_fl, x_bf, bg, (void*)g2, nullptr, nullptr, nullptr);
  k_gemm<256, kCIV, 1, 512><<<dim3(25, 1, 32), 512, 0, stream>>>(
      f_bf, g2, nullptr, (void*)yb, nullptr, nullptr, nullptr);
  k_syy<<<SYY_B, 256, 0, stream>>>(yb, psyy, psy);
  k_reduce<<<65, 256, 0, stream>>>(psyy, psy, syy, sy);
  k_stats<<<256, 128, 0, stream>>>(syy, sy, Ww, bw, gamma, beta, scale, shift);
  k_gemm<128, kTV, 2, 512><<<dim3(50, 1, 32), 512, 0, stream>>>(
      Ww_fl, yb, nullptr, (void*)out, scale, shift, x_bf);
}